// Round 3
// baseline (325.971 us; speedup 1.0000x reference)
//
#include <hip/hip_runtime.h>
#include <hip/hip_bf16.h>

// Problem: out[i,j] = sigmoid(W3·gelu(W2·gelu(W1·[p1_i,p2_j,p1_i-p2_j]+b1)+b2)+b3)
// Key algebra: layer1 factorizes: h1[i,j] = u_i + v_j  (b1 folded into u)
//   u = p1@(W1[0:256]+W1[512:768]) + b1 ;  v = p2@(W1[256:512]-W1[512:768])
// Remaining heavy op: [65536 x 1024] @ [1024 x 512] bf16 MFMA GEMM, fused epilogue.

#define N1 256
#define N2 256
#define LTOK 128
#define DDIM 256
#define DENSEU 1024
#define HID 512

typedef float f32x4 __attribute__((ext_vector_type(4)));
typedef short s16x8 __attribute__((ext_vector_type(8)));   // 8 bf16 (guide-verified frag type)

__device__ __forceinline__ short f2bf(float x) {
  union { __bf16 b; short s; } cv;
  cv.b = (__bf16)x;
  return cv.s;
}

__device__ __forceinline__ float gelu_fast(float x) {
  // tanh-form GELU; |err| vs exact erf-GELU <~1e-3 at these magnitudes,
  // output impact ~1e-4 (<< 0.01 threshold)
  float x3 = x * x * x;
  float z = 0.7978845608028654f * (x + 0.044715f * x3);
  float e = __expf(2.0f * z);
  float t = 1.0f - 2.0f / (e + 1.0f);
  return 0.5f * x * (1.0f + t);
}

// ---------------- sentinel: ws_size too small (diagnostic) ----------------
__global__ void sentinel_kernel(float* out, int n) {
  int i = blockIdx.x * blockDim.x + threadIdx.x;
  if (i < n) out[i] = 123.0f;
}

// ---------------- kernel 1: mean-pool over L ----------------
__global__ __launch_bounds__(256) void pool_kernel(const float* __restrict__ f1,
                                                   const float* __restrict__ f2,
                                                   float* __restrict__ p1,
                                                   float* __restrict__ p2) {
  __shared__ float4 red[256];
  int b = blockIdx.x;
  int tensor = b >> 8;
  int n = b & 255;
  const float* src = tensor ? f2 : f1;
  float* dst = tensor ? p2 : p1;
  int t = threadIdx.x;
  int d4 = (t & 63) * 4;
  int l0 = t >> 6;  // 4 wave-groups split the L range
  const float4* base = (const float4*)(src + (size_t)n * (LTOK * DDIM) + d4);
  float4 s = {0.f, 0.f, 0.f, 0.f};
  #pragma unroll 8
  for (int l = l0; l < LTOK; l += 4) {
    float4 x = base[l * (DDIM / 4)];
    s.x += x.x; s.y += x.y; s.z += x.z; s.w += x.w;
  }
  red[t] = s;
  __syncthreads();
  if (t < 64) {
    float4 a = red[t], b4 = red[t + 64], c = red[t + 128], d = red[t + 192];
    float4 r;
    r.x = (a.x + b4.x + c.x + d.x) * (1.f / LTOK);
    r.y = (a.y + b4.y + c.y + d.y) * (1.f / LTOK);
    r.z = (a.z + b4.z + c.z + d.z) * (1.f / LTOK);
    r.w = (a.w + b4.w + c.w + d.w) * (1.f / LTOK);
    ((float4*)(dst + (size_t)n * DDIM))[t] = r;
  }
}

// ---------------- kernel 2: u = p1@(W1a+W1c)+b1 ; v = p2@(W1b-W1c) ----------------
__global__ __launch_bounds__(256) void uv_kernel(const float* __restrict__ p1,
                                                 const float* __restrict__ p2,
                                                 const float* __restrict__ W1,
                                                 const float* __restrict__ b1,
                                                 float* __restrict__ u,
                                                 float* __restrict__ v) {
  __shared__ float pl[16][DDIM];
  int t = threadIdx.x;
  int o = blockIdx.x * 256 + t;      // 0..1023
  int n0 = blockIdx.y * 16;          // 0..240
  int tensor = blockIdx.z;           // 0=u, 1=v
  const float* p = tensor ? p2 : p1;
  #pragma unroll
  for (int r = 0; r < 16; ++r) pl[r][t] = p[(size_t)(n0 + r) * DDIM + t];
  __syncthreads();
  const float* wa = W1 + (tensor ? (256 * DENSEU) : 0);
  const float* wc = W1 + 512 * DENSEU;
  float sgn = tensor ? -1.0f : 1.0f;
  float acc[16];
  #pragma unroll
  for (int nn = 0; nn < 16; ++nn) acc[nn] = 0.f;
  for (int d = 0; d < DDIM; ++d) {
    float w = wa[(size_t)d * DENSEU + o] + sgn * wc[(size_t)d * DENSEU + o];
    #pragma unroll
    for (int nn = 0; nn < 16; ++nn) acc[nn] += pl[nn][d] * w;
  }
  float* dst = tensor ? v : u;
  float bb = tensor ? 0.f : b1[o];
  #pragma unroll
  for (int nn = 0; nn < 16; ++nn) dst[(size_t)(n0 + nn) * DENSEU + o] = acc[nn] + bb;
}

// ---------------- kernel 3: W2 [1024x512] f32 -> W2T [512x1024] bf16 ----------------
__global__ __launch_bounds__(256) void w2t_kernel(const float* __restrict__ W2,
                                                  unsigned short* __restrict__ w2t) {
  __shared__ float tile[32][33];
  int tx = threadIdx.x, ty = threadIdx.y;   // 32 x 8
  int n0 = blockIdx.x * 32, k0 = blockIdx.y * 32;
  #pragma unroll
  for (int r = 0; r < 4; ++r) {
    int kk = ty + r * 8;
    tile[kk][tx] = W2[(size_t)(k0 + kk) * HID + n0 + tx];
  }
  __syncthreads();
  #pragma unroll
  for (int r = 0; r < 4; ++r) {
    int nn = ty + r * 8;
    w2t[(size_t)(n0 + nn) * DENSEU + k0 + tx] = (unsigned short)f2bf(tile[tx][nn]);
  }
}

// ---------------- kernel 4: fused x1-build + GEMM2 + epilogue ----------------
// block: 512 thr (8 waves). BM=64 rows (one i, 64 consecutive j), BN=512 (full),
// wave w owns n-slice [w*64, w*64+64). BK=64, 16 K-steps. x1 tile in swizzled LDS.
__global__ __launch_bounds__(512) void fused_kernel(const float* __restrict__ u,
                                                    const float* __restrict__ v,
                                                    const unsigned short* __restrict__ w2t,
                                                    const float* __restrict__ b2,
                                                    const float* __restrict__ W3,
                                                    const float* __restrict__ b3,
                                                    float* __restrict__ out) {
  __shared__ __align__(16) unsigned char xs[64 * 128];  // 64 rows x 64 bf16, XOR-swizzled
  __shared__ float rowsum[64];
  int tid = threadIdx.x;
  int lane = tid & 63;
  int wave = tid >> 6;
  int i = blockIdx.x >> 2;
  int j0 = (blockIdx.x & 3) * 64;
  int woff = wave * 64;

  // build-phase mapping: each thread produces 8 consecutive k for one row
  int brow = tid >> 3;  // 0..63
  int bkg = tid & 7;    // k-group of 8
  const float* urow = u + (size_t)i * DENSEU;
  const float* vrow = v + (size_t)(j0 + brow) * DENSEU;
  unsigned wbyte = (unsigned)(brow * 128) + (((unsigned)bkg << 4) ^ ((unsigned)(brow & 7) << 4));

  // A-frag addressing (row = mf*16 + lane&15, k-chunk by lane>>4, swizzled)
  unsigned rbase[4], rswz[4];
  #pragma unroll
  for (int mf = 0; mf < 4; ++mf) {
    int r = mf * 16 + (lane & 15);
    rbase[mf] = (unsigned)(r * 128);
    rswz[mf] = (unsigned)((r & 7) << 4);
  }
  unsigned klane = (unsigned)((lane >> 4) << 4);

  int bn[4];
  #pragma unroll
  for (int nf = 0; nf < 4; ++nf) bn[nf] = woff + nf * 16 + (lane & 15);

  f32x4 acc[4][4];
  f32x4 zero = {0.f, 0.f, 0.f, 0.f};
  #pragma unroll
  for (int mf = 0; mf < 4; ++mf)
    #pragma unroll
    for (int nf = 0; nf < 4; ++nf) acc[mf][nf] = zero;

  for (int kt = 0; kt < 16; ++kt) {
    int kkb = kt * 64 + bkg * 8;
    float4 ua = *(const float4*)(urow + kkb);
    float4 ub = *(const float4*)(urow + kkb + 4);
    float4 va = *(const float4*)(vrow + kkb);
    float4 vb = *(const float4*)(vrow + kkb + 4);
    float fv[8] = {ua.x + va.x, ua.y + va.y, ua.z + va.z, ua.w + va.w,
                   ub.x + vb.x, ub.y + vb.y, ub.z + vb.z, ub.w + vb.w};
    s16x8 pk;
    #pragma unroll
    for (int e = 0; e < 8; ++e) pk[e] = f2bf(gelu_fast(fv[e]));
    __syncthreads();                       // prior K-step's LDS reads done
    *(s16x8*)(xs + wbyte) = pk;
    __syncthreads();                       // tile ready

    int kglob = kt * 64 + ((lane >> 4) << 3);
    #pragma unroll
    for (int ksub = 0; ksub < 2; ++ksub) {
      s16x8 af[4];
      #pragma unroll
      for (int mf = 0; mf < 4; ++mf) {
        unsigned off = rbase[mf] + ((((unsigned)ksub << 6) | klane) ^ rswz[mf]);
        af[mf] = *(const s16x8*)(xs + off);
      }
      s16x8 bfr[4];
      #pragma unroll
      for (int nf = 0; nf < 4; ++nf)
        bfr[nf] = *(const s16x8*)(w2t + (size_t)bn[nf] * DENSEU + kglob + ksub * 32);
      #pragma unroll
      for (int mf = 0; mf < 4; ++mf)
        #pragma unroll
        for (int nf = 0; nf < 4; ++nf)
          acc[mf][nf] = __builtin_amdgcn_mfma_f32_16x16x32_bf16(af[mf], bfr[nf], acc[mf][nf], 0, 0, 0);
    }
  }

  // epilogue: h2 -> +b2 -> gelu -> *W3 -> row-reduce -> +b3 -> sigmoid
  if (tid < 64) rowsum[tid] = 0.f;
  __syncthreads();
  float b2v[4], w3v[4];
  #pragma unroll
  for (int nf = 0; nf < 4; ++nf) { b2v[nf] = b2[bn[nf]]; w3v[nf] = W3[bn[nf]]; }
  int qr = lane >> 4;
  #pragma unroll
  for (int mf = 0; mf < 4; ++mf) {
    #pragma unroll
    for (int j = 0; j < 4; ++j) {
      float part = 0.f;
      #pragma unroll
      for (int nf = 0; nf < 4; ++nf) {
        float h = acc[mf][nf][j] + b2v[nf];
        part += gelu_fast(h) * w3v[nf];
      }
      part += __shfl_xor(part, 1);
      part += __shfl_xor(part, 2);
      part += __shfl_xor(part, 4);
      part += __shfl_xor(part, 8);
      if ((lane & 15) == 0) atomicAdd(&rowsum[mf * 16 + qr * 4 + j], part);
    }
  }
  __syncthreads();
  if (tid < 64) {
    float s = rowsum[tid] + b3[0];
    out[(size_t)i * N2 + j0 + tid] = 1.0f / (1.0f + __expf(-s));
  }
}

extern "C" void kernel_launch(void* const* d_in, const int* in_sizes, int n_in,
                              void* d_out, int out_size, void* d_ws, size_t ws_size,
                              hipStream_t stream) {
  const float* f1 = (const float*)d_in[0];
  const float* f2 = (const float*)d_in[1];
  const float* W1 = (const float*)d_in[2];
  const float* b1 = (const float*)d_in[3];
  const float* W2 = (const float*)d_in[4];
  const float* b2 = (const float*)d_in[5];
  const float* W3 = (const float*)d_in[6];
  const float* b3 = (const float*)d_in[7];
  float* out = (float*)d_out;

  // workspace layout (floats): p1[64K] p2[64K] u[256K] v[256K] + w2t bf16[512K]
  size_t need_bytes = (size_t)(256 * 256 * 2 + 256 * 1024 * 2) * sizeof(float)
                    + (size_t)(512 * 1024) * sizeof(unsigned short);
  if (n_in < 8 || ws_size < need_bytes) {
    // Diagnostic sentinel: absmax ~122 next round => workspace too small.
    sentinel_kernel<<<(out_size + 255) / 256, 256, 0, stream>>>(out, out_size);
    return;
  }

  float* p1 = (float*)d_ws;                       // 256*256 f32
  float* p2 = p1 + 256 * 256;                     // 256*256 f32
  float* u  = p2 + 256 * 256;                     // 256*1024 f32 (b1 folded in)
  float* v  = u + 256 * 1024;                     // 256*1024 f32
  unsigned short* w2t = (unsigned short*)(v + 256 * 1024);  // 512*1024 bf16

  pool_kernel<<<512, 256, 0, stream>>>(f1, f2, p1, p2);
  uv_kernel<<<dim3(4, 16, 2), 256, 0, stream>>>(p1, p2, W1, b1, u, v);
  w2t_kernel<<<dim3(16, 32), dim3(32, 8), 0, stream>>>(W2, w2t);
  fused_kernel<<<1024, 512, 0, stream>>>(u, v, w2t, b2, W3, b3, out);
}

// Round 6
// 304.119 us; speedup vs baseline: 1.0719x; 1.0719x over previous
//
#include <hip/hip_runtime.h>
#include <hip/hip_bf16.h>

// out[i,j] = sigmoid(W3·gelu(W2·gelu(W1·[p1_i,p2_j,p1_i-p2_j]+b1)+b2)+b3)
// Layer-1 factorizes: h1[i,j] = u_i + v_j (b1 folded into u).
// Heavy op: [65536 x 1024] @ [1024 x 512] bf16 MFMA GEMM with on-the-fly
// x1 = gelu(u_i + v_j) tile build (double-buffered LDS, 1 barrier/K-step),
// register-double-buffered B-fragments, fused gelu/W3/sigmoid epilogue.

#define N1 256
#define N2 256
#define LTOK 128
#define DDIM 256
#define DENSEU 1024
#define HID 512

typedef float f32x4 __attribute__((ext_vector_type(4)));
typedef short s16x8 __attribute__((ext_vector_type(8)));   // 8 bf16

__device__ __forceinline__ short f2bf(float x) {
  union { __bf16 b; short s; } cv; cv.b = (__bf16)x; return cv.s;
}

__device__ __forceinline__ float fast_rcp(float x) {
#if __has_builtin(__builtin_amdgcn_rcpf)
  return __builtin_amdgcn_rcpf(x);
#else
  return 1.0f / x;
#endif
}

// gelu(x) = x * sigmoid(2z), z = sqrt(2/pi)*(x + 0.044715 x^3)
// == tanh-form gelu exactly; ~9 VALU ops (1 exp, 1 rcp).
__device__ __forceinline__ float gelu_fast(float x) {
  float t = x * x;
  float z2 = x * fmaf(0.0713548162726f, t, 1.5957691216057308f);  // 2z
  float e = __expf(z2);
  return x * e * fast_rcp(e + 1.0f);
}

// ---------------- sentinel: ws_size too small (diagnostic) ----------------
__global__ void sentinel_kernel(float* out, int n) {
  int i = blockIdx.x * blockDim.x + threadIdx.x;
  if (i < n) out[i] = 123.0f;
}

// ---------------- kernel 1: mean-pool over L ----------------
__global__ __launch_bounds__(256) void pool_kernel(const float* __restrict__ f1,
                                                   const float* __restrict__ f2,
                                                   float* __restrict__ p1,
                                                   float* __restrict__ p2) {
  __shared__ float4 red[256];
  int b = blockIdx.x;
  int tensor = b >> 8;
  int n = b & 255;
  const float* src = tensor ? f2 : f1;
  float* dst = tensor ? p2 : p1;
  int t = threadIdx.x;
  int d4 = (t & 63) * 4;
  int l0 = t >> 6;
  const float4* base = (const float4*)(src + (size_t)n * (LTOK * DDIM) + d4);
  float4 s = {0.f, 0.f, 0.f, 0.f};
  #pragma unroll 8
  for (int l = l0; l < LTOK; l += 4) {
    float4 x = base[l * (DDIM / 4)];
    s.x += x.x; s.y += x.y; s.z += x.z; s.w += x.w;
  }
  red[t] = s;
  __syncthreads();
  if (t < 64) {
    float4 a = red[t], b4 = red[t + 64], c = red[t + 128], d = red[t + 192];
    float4 r;
    r.x = (a.x + b4.x + c.x + d.x) * (1.f / LTOK);
    r.y = (a.y + b4.y + c.y + d.y) * (1.f / LTOK);
    r.z = (a.z + b4.z + c.z + d.z) * (1.f / LTOK);
    r.w = (a.w + b4.w + c.w + d.w) * (1.f / LTOK);
    ((float4*)(dst + (size_t)n * DDIM))[t] = r;
  }
}

// ---------------- kernel 2: u = p1@(W1a+W1c)+b1 ; v = p2@(W1b-W1c) ----------------
__global__ __launch_bounds__(256) void uv_kernel(const float* __restrict__ p1,
                                                 const float* __restrict__ p2,
                                                 const float* __restrict__ W1,
                                                 const float* __restrict__ b1,
                                                 float* __restrict__ u,
                                                 float* __restrict__ v) {
  __shared__ float pl[16][DDIM];
  int t = threadIdx.x;
  int o = blockIdx.x * 256 + t;
  int n0 = blockIdx.y * 16;
  int tensor = blockIdx.z;
  const float* p = tensor ? p2 : p1;
  #pragma unroll
  for (int r = 0; r < 16; ++r) pl[r][t] = p[(size_t)(n0 + r) * DDIM + t];
  __syncthreads();
  const float* wa = W1 + (tensor ? (256 * DENSEU) : 0);
  const float* wc = W1 + 512 * DENSEU;
  float sgn = tensor ? -1.0f : 1.0f;
  float acc[16];
  #pragma unroll
  for (int nn = 0; nn < 16; ++nn) acc[nn] = 0.f;
  for (int d = 0; d < DDIM; ++d) {
    float w = wa[(size_t)d * DENSEU + o] + sgn * wc[(size_t)d * DENSEU + o];
    #pragma unroll
    for (int nn = 0; nn < 16; ++nn) acc[nn] += pl[nn][d] * w;
  }
  float* dst = tensor ? v : u;
  float bb = tensor ? 0.f : b1[o];
  #pragma unroll
  for (int nn = 0; nn < 16; ++nn) dst[(size_t)(n0 + nn) * DENSEU + o] = acc[nn] + bb;
}

// ---------------- kernel 3: W2 [1024x512] f32 -> W2T [512x1024] bf16 ----------------
__global__ __launch_bounds__(256) void w2t_kernel(const float* __restrict__ W2,
                                                  unsigned short* __restrict__ w2t) {
  __shared__ float tile[32][33];
  int tx = threadIdx.x, ty = threadIdx.y;   // 32 x 8
  int n0 = blockIdx.x * 32, k0 = blockIdx.y * 32;
  #pragma unroll
  for (int r = 0; r < 4; ++r) {
    int kk = ty + r * 8;
    tile[kk][tx] = W2[(size_t)(k0 + kk) * HID + n0 + tx];
  }
  __syncthreads();
  #pragma unroll
  for (int r = 0; r < 4; ++r) {
    int nn = ty + r * 8;
    w2t[(size_t)(n0 + nn) * DENSEU + k0 + tx] = (unsigned short)f2bf(tile[tx][nn]);
  }
}

// ---------------- kernel 4: fused x1-build + GEMM2 + epilogue ----------------
// 512 thr (8 waves). BM=64 rows (one i, 64 j), BN=512, wave w owns n-slice
// [w*64, w*64+64). BK=64, 16 K-steps. Double-buffered swizzled x1 LDS tile,
// register-double-buffered B fragments, one barrier per K-step.
__global__ __launch_bounds__(512, 2) void fused_kernel(const float* __restrict__ u,
                                                       const float* __restrict__ v,
                                                       const unsigned short* __restrict__ w2t,
                                                       const float* __restrict__ b2,
                                                       const float* __restrict__ W3,
                                                       const float* __restrict__ b3,
                                                       float* __restrict__ out) {
  __shared__ __align__(16) unsigned char xs[2][64 * 128];  // 2 x (64 rows x 64 bf16), XOR-swizzled
  __shared__ __align__(16) float u_lds[DENSEU];
  __shared__ float rowsum[64];
  const int tid = threadIdx.x;
  const int lane = tid & 63;
  const int wave = tid >> 6;
  const int i = blockIdx.x >> 2;
  const int j0 = (blockIdx.x & 3) * 64;
  const int woff = wave * 64;
  const int brow = tid >> 3;   // build row 0..63
  const int bkg = tid & 7;     // build k-group of 8
  const float* urow = u + (size_t)i * DENSEU;
  const float* vrow = v + (size_t)(j0 + brow) * DENSEU;

  // stage u row into LDS (4 KB), zero rowsum
  if (tid < 256) ((f32x4*)u_lds)[tid] = ((const f32x4*)urow)[tid];
  if (tid < 64) rowsum[tid] = 0.f;

  const unsigned wbyte = (unsigned)(brow * 128) +
                         (((unsigned)bkg << 4) ^ ((unsigned)(brow & 7) << 4));
  unsigned aoff0[4];
  #pragma unroll
  for (int mf = 0; mf < 4; ++mf) {
    int r = mf * 16 + (lane & 15);
    aoff0[mf] = (unsigned)(r * 128) +
                ((((unsigned)(lane >> 4)) << 4) ^ ((unsigned)(r & 7) << 4));
  }
  const int kl8 = (lane >> 4) * 8;
  int bnbase[4];
  #pragma unroll
  for (int nf = 0; nf < 4; ++nf) bnbase[nf] = (woff + nf * 16 + (lane & 15)) * DENSEU;

  __syncthreads();  // u_lds ready

  // build K-step 0 tile
  {
    float4 va = *(const float4*)(vrow + bkg * 8);
    float4 vb = *(const float4*)(vrow + bkg * 8 + 4);
    float4 ua = *(const float4*)(u_lds + bkg * 8);
    float4 ub = *(const float4*)(u_lds + bkg * 8 + 4);
    s16x8 pk;
    pk[0] = f2bf(gelu_fast(ua.x + va.x));
    pk[1] = f2bf(gelu_fast(ua.y + va.y));
    pk[2] = f2bf(gelu_fast(ua.z + va.z));
    pk[3] = f2bf(gelu_fast(ua.w + va.w));
    pk[4] = f2bf(gelu_fast(ub.x + vb.x));
    pk[5] = f2bf(gelu_fast(ub.y + vb.y));
    pk[6] = f2bf(gelu_fast(ub.z + vb.z));
    pk[7] = f2bf(gelu_fast(ub.w + vb.w));
    *(s16x8*)(xs[0] + wbyte) = pk;
  }

  // preload B fragments for K-step 0
  s16x8 bcur[8], bnxt[8];
  #pragma unroll
  for (int q = 0; q < 8; ++q)
    bcur[q] = *(const s16x8*)(w2t + bnbase[q & 3] + (q >> 2) * 32 + kl8);

  f32x4 acc[4][4];
  #pragma unroll
  for (int mf = 0; mf < 4; ++mf)
    #pragma unroll
    for (int nf = 0; nf < 4; ++nf) {
      f32x4 z = {0.f, 0.f, 0.f, 0.f};
      acc[mf][nf] = z;
    }

  __syncthreads();  // xs[0] ready

  // One K-step: prefetch v/B for kt+1, MFMA on xs[RB] with BC, build kt+1
  // into xs[WB], single barrier. Last step wraps (&15) harmlessly.
#define KSTEP(KT, RB, WB, BC, BN_)                                            \
  {                                                                           \
    const int ktn = ((KT) + 1) & 15;                                          \
    const int kb = ktn * 64 + bkg * 8;                                        \
    float4 va = *(const float4*)(vrow + kb);                                  \
    float4 vb = *(const float4*)(vrow + kb + 4);                              \
    _Pragma("unroll")                                                         \
    for (int q = 0; q < 8; ++q)                                               \
      BN_[q] = *(const s16x8*)(w2t + bnbase[q & 3] + ktn * 64 + (q >> 2) * 32 + kl8); \
    s16x8 af[8];                                                              \
    _Pragma("unroll")                                                         \
    for (int mf = 0; mf < 4; ++mf) {                                          \
      af[mf] = *(const s16x8*)(xs[RB] + aoff0[mf]);                           \
      af[4 + mf] = *(const s16x8*)(xs[RB] + (aoff0[mf] ^ 64));                \
    }                                                                         \
    _Pragma("unroll")                                                         \
    for (int mf = 0; mf < 4; ++mf)                                            \
      _Pragma("unroll")                                                       \
      for (int nf = 0; nf < 4; ++nf)                                          \
        acc[mf][nf] = __builtin_amdgcn_mfma_f32_16x16x32_bf16(af[mf], BC[nf], acc[mf][nf], 0, 0, 0); \
    _Pragma("unroll")                                                         \
    for (int mf = 0; mf < 4; ++mf)                                            \
      _Pragma("unroll")                                                       \
      for (int nf = 0; nf < 4; ++nf)                                          \
        acc[mf][nf] = __builtin_amdgcn_mfma_f32_16x16x32_bf16(af[4 + mf], BC[4 + nf], acc[mf][nf], 0, 0, 0); \
    float4 ua = *(const float4*)(u_lds + kb);                                 \
    float4 ub = *(const float4*)(u_lds + kb + 4);                             \
    s16x8 pk;                                                                 \
    pk[0] = f2bf(gelu_fast(ua.x + va.x));                                     \
    pk[1] = f2bf(gelu_fast(ua.y + va.y));                                     \
    pk[2] = f2bf(gelu_fast(ua.z + va.z));                                     \
    pk[3] = f2bf(gelu_fast(ua.w + va.w));                                     \
    pk[4] = f2bf(gelu_fast(ub.x + vb.x));                                     \
    pk[5] = f2bf(gelu_fast(ub.y + vb.y));                                     \
    pk[6] = f2bf(gelu_fast(ub.z + vb.z));                                     \
    pk[7] = f2bf(gelu_fast(ub.w + vb.w));                                     \
    *(s16x8*)(xs[WB] + wbyte) = pk;                                           \
    __syncthreads();                                                          \
  }

  for (int kt2 = 0; kt2 < 8; ++kt2) {
    KSTEP(kt2 * 2, 0, 1, bcur, bnxt)
    KSTEP(kt2 * 2 + 1, 1, 0, bnxt, bcur)
  }
#undef KSTEP

  // epilogue: h2 -> +b2 -> gelu -> *W3 -> row-reduce -> +b3 -> sigmoid
  float b2v[4], w3v[4];
  #pragma unroll
  for (int nf = 0; nf < 4; ++nf) {
    int bnn = woff + nf * 16 + (lane & 15);
    b2v[nf] = b2[bnn];
    w3v[nf] = W3[bnn];
  }
  int qr = lane >> 4;
  #pragma unroll
  for (int mf = 0; mf < 4; ++mf) {
    #pragma unroll
    for (int j = 0; j < 4; ++j) {
      float part = 0.f;
      #pragma unroll
      for (int nf = 0; nf < 4; ++nf) {
        float h = acc[mf][nf][j] + b2v[nf];
        part += gelu_fast(h) * w3v[nf];
      }
      part += __shfl_xor(part, 1);
      part += __shfl_xor(part, 2);
      part += __shfl_xor(part, 4);
      part += __shfl_xor(part, 8);
      if ((lane & 15) == 0) atomicAdd(&rowsum[mf * 16 + qr * 4 + j], part);
    }
  }
  __syncthreads();
  if (tid < 64) {
    float s = rowsum[tid] + b3[0];
    out[(size_t)i * N2 + j0 + tid] = fast_rcp(1.0f + __expf(-s));
  }
}

extern "C" void kernel_launch(void* const* d_in, const int* in_sizes, int n_in,
                              void* d_out, int out_size, void* d_ws, size_t ws_size,
                              hipStream_t stream) {
  const float* f1 = (const float*)d_in[0];
  const float* f2 = (const float*)d_in[1];
  const float* W1 = (const float*)d_in[2];
  const float* b1 = (const float*)d_in[3];
  const float* W2 = (const float*)d_in[4];
  const float* b2 = (const float*)d_in[5];
  const float* W3 = (const float*)d_in[6];
  const float* b3 = (const float*)d_in[7];
  float* out = (float*)d_out;

  size_t need_bytes = (size_t)(256 * 256 * 2 + 256 * 1024 * 2) * sizeof(float)
                    + (size_t)(512 * 1024) * sizeof(unsigned short);
  if (n_in < 8 || ws_size < need_bytes) {
    sentinel_kernel<<<(out_size + 255) / 256, 256, 0, stream>>>(out, out_size);
    return;
  }

  float* p1 = (float*)d_ws;                       // 256*256 f32
  float* p2 = p1 + 256 * 256;                     // 256*256 f32
  float* u  = p2 + 256 * 256;                     // 256*1024 f32 (b1 folded in)
  float* v  = u + 256 * 1024;                     // 256*1024 f32
  unsigned short* w2t = (unsigned short*)(v + 256 * 1024);  // 512*1024 bf16

  pool_kernel<<<512, 256, 0, stream>>>(f1, f2, p1, p2);
  uv_kernel<<<dim3(4, 16, 2), 256, 0, stream>>>(p1, p2, W1, b1, u, v);
  w2t_kernel<<<dim3(16, 32), dim3(32, 8), 0, stream>>>(W2, w2t);
  fused_kernel<<<1024, 512, 0, stream>>>(u, v, w2t, b2, W3, b3, out);
}